// Round 21
// baseline (89.861 us; speedup 1.0000x reference)
//
#include <hip/hip_runtime.h>

#define B_   4
#define S_   1024
#define D_   768
#define H_   12
#define HD_  64
#define NROW (B_*S_)          // 4096
#define RSTRIDE (H_*HD_)      // 768
#define NBH  (B_*H_)          // 48
#define LOG2E 1.44269504f

typedef __bf16 bf16_t;
typedef bf16_t bf16x8 __attribute__((ext_vector_type(8)));
typedef float  f32x4  __attribute__((ext_vector_type(4)));
typedef float  f32x16 __attribute__((ext_vector_type(16)));
typedef unsigned int u32x4 __attribute__((ext_vector_type(4)));

__device__ __forceinline__ unsigned short bf16b(float f){
  bf16_t b = (bf16_t)f;
  return __builtin_bit_cast(unsigned short, b);
}

__device__ __forceinline__ void gload16(const void* g, void* l){
  __builtin_amdgcn_global_load_lds(
      (const __attribute__((address_space(1))) void*)g,
      (__attribute__((address_space(3))) void*)l, 16, 0, 0);
}

__device__ __forceinline__ unsigned int cvtpk(float lo, float hi){
  unsigned int r;
  asm("v_cvt_pk_bf16_f32 %0, %1, %2" : "=v"(r) : "v"(lo), "v"(hi));
  return r;
}

__device__ __forceinline__ void plswap(unsigned int &a, unsigned int &b){
  asm volatile("v_permlane32_swap_b32 %0, %1" : "+v"(a), "+v"(b));
}

// ---- frag48 layout: X[R][768] element (row,k) lives at
//   ((row>>5)*48 + (k>>4))*512 + ((k>>3)&1)*256 + (row&31)*8 + (k&7)
// A wave reading base(rowtile) + c*512 + lane*8 gets X[rt*32+lq][c*16+hi*8+j],
// exactly the attention qf/kf fragment pattern (verified since R7).
__device__ __forceinline__ size_t frag48_addr(int row, int k){
  return ((size_t)((row>>5)*48 + (k>>4)))*512 + ((k>>3)&1)*256 + (row&31)*8 + (k&7);
}

// ---------------- fused prep: RMSNorm(q)->frag48 + casts->frag48/rowmajor ----------------
__global__ void prep_kernel(const float* __restrict__ q, const float* __restrict__ w_norm,
                            bf16_t* __restrict__ qnf,
                            const float* __restrict__ wq,  bf16_t* __restrict__ wqf,
                            const float* __restrict__ wkv, bf16_t* __restrict__ wkvf,
                            const float* __restrict__ wo,  bf16_t* __restrict__ wob,
                            const float* __restrict__ kv,  bf16_t* __restrict__ kvbf){
  int bid = blockIdx.x;
  if (bid < NROW){
    int row = bid;
    const float* src = q + (size_t)row*D_;
    float vals[3]; float ss = 0.f;
#pragma unroll
    for (int i=0;i<3;i++){ float v = src[threadIdx.x + i*256]; vals[i]=v; ss += v*v; }
#pragma unroll
    for (int m=1;m<64;m<<=1) ss += __shfl_xor(ss, m, 64);
    __shared__ float red[4];
    if ((threadIdx.x & 63) == 0) red[threadIdx.x>>6] = ss;
    __syncthreads();
    float tot = red[0]+red[1]+red[2]+red[3];
    float rs = rsqrtf(tot*(1.0f/D_) + 1e-5f);
#pragma unroll
    for (int i=0;i<3;i++){
      int c = threadIdx.x + i*256;
      qnf[frag48_addr(row, c)] = (bf16_t)(vals[i]*rs*w_norm[c]);
    }
  } else {
    int i = (bid - NROW)*256 + threadIdx.x;
    const int n0 = D_*D_/4, n1 = 2*D_*D_/4, n2 = D_*D_/4, n3 = NROW*D_/4;
    if (i < n0 + n1 + n3 && i < n0 + n1 || i >= n0 + n1 + n2 || i < n0){} // (no-op; clarity below)
    if (i < n0){                       // w_q -> wfrag48
      float4 v = reinterpret_cast<const float4*>(wq)[i];
      int e0 = i*4, row = e0/768, k = e0%768;
      ushort4 o; o.x=bf16b(v.x); o.y=bf16b(v.y); o.z=bf16b(v.z); o.w=bf16b(v.w);
      *reinterpret_cast<ushort4*>(wqf + frag48_addr(row,k)) = o;
    } else if (i < n0+n1){             // w_kv -> wfrag48
      int off = i - n0;
      float4 v = reinterpret_cast<const float4*>(wkv)[off];
      int e0 = off*4, row = e0/768, k = e0%768;
      ushort4 o; o.x=bf16b(v.x); o.y=bf16b(v.y); o.z=bf16b(v.z); o.w=bf16b(v.w);
      *reinterpret_cast<ushort4*>(wkvf + frag48_addr(row,k)) = o;
    } else if (i < n0+n1+n2){          // w_out -> row-major bf16 (gemm_out LDS path)
      int off = i - n0 - n1;
      float4 v = reinterpret_cast<const float4*>(wo)[off];
      ushort4 o; o.x=bf16b(v.x); o.y=bf16b(v.y); o.z=bf16b(v.z); o.w=bf16b(v.w);
      reinterpret_cast<ushort4*>(wob)[off] = o;
    } else if (i < n0+n1+n2+n3){       // kv -> afrag48
      int off = i - n0 - n1 - n2;
      float4 v = reinterpret_cast<const float4*>(kv)[off];
      int e0 = off*4, row = e0/768, k = e0%768;
      ushort4 o; o.x=bf16b(v.x); o.y=bf16b(v.y); o.z=bf16b(v.z); o.w=bf16b(v.w);
      *reinterpret_cast<ushort4*>(kvbf + frag48_addr(row,k)) = o;
    }
  }
}

// ---------------- gemm_qkv: NO-LDS fragment streaming (attn-style) ----------------
// 576 blocks x 256 thr; wave = 64x64 output tile (2 row-frags x 2 col-frags).
// acc[nt][rt][r] = C[n = ntg*32 + crow(r,hi)][row = rtg*32 + lq]  (verified attn mapping)
// Epilogues: RoPE pairs are IN-LANE (crow(r), crow(r)+1 adjacent for even r&3).
__global__ __launch_bounds__(256, 3)
void gemm_qkv_kernel(const bf16_t* __restrict__ qnf, const bf16_t* __restrict__ kvbf,
                     const bf16_t* __restrict__ wqf, const bf16_t* __restrict__ wkvf,
                     const float* __restrict__ bq, const float* __restrict__ bkv,
                     const int* __restrict__ posq, const int* __restrict__ posk,
                     const float* __restrict__ freqs,
                     bf16_t* __restrict__ qh, bf16_t* __restrict__ kh,
                     bf16_t* __restrict__ vfrag){
  const int lane = threadIdx.x & 63;
  const int wv   = threadIdx.x >> 6;
  const int hi = lane >> 5, lq = lane & 31;
  int l = ((int)blockIdx.x & 7)*72 + ((int)blockIdx.x >> 3);  // 576 = 8*72
  const int x = l & 31, y = l >> 5;  // x: 32 row tiles (128 rows), y: 18 col tiles (128 cols)
  const int wr = wv >> 1, wc = wv & 1;
  const int rt0 = x*4 + wr*2;        // 32-row tiles rt0, rt0+1 (of 128)
  const bf16_t* Af; const bf16_t* Wf; const float* bias; const int* pos; int ntbase;
  if (y < 6){ Af = qnf; Wf = wqf;  bias = bq;  pos = posq; ntbase = y*4 + wc*2; }
  else      { Af = kvbf; Wf = wkvf; bias = bkv; pos = posk; ntbase = (y-6)*4 + wc*2; }

  const bf16_t* a0 = Af + ((size_t)(rt0  )*48)*512 + lane*8;
  const bf16_t* a1 = Af + ((size_t)(rt0+1)*48)*512 + lane*8;
  const bf16_t* w0 = Wf + ((size_t)(ntbase  )*48)*512 + lane*8;
  const bf16_t* w1 = Wf + ((size_t)(ntbase+1)*48)*512 + lane*8;

  f32x16 acc[2][2] = {};   // [nt][rt]
#pragma unroll 4
  for (int c=0;c<48;c++){
    bf16x8 A0 = *reinterpret_cast<const bf16x8*>(a0 + (size_t)c*512);
    bf16x8 A1 = *reinterpret_cast<const bf16x8*>(a1 + (size_t)c*512);
    bf16x8 W0 = *reinterpret_cast<const bf16x8*>(w0 + (size_t)c*512);
    bf16x8 W1 = *reinterpret_cast<const bf16x8*>(w1 + (size_t)c*512);
    acc[0][0] = __builtin_amdgcn_mfma_f32_32x32x16_bf16(W0, A0, acc[0][0], 0,0,0);
    acc[0][1] = __builtin_amdgcn_mfma_f32_32x32x16_bf16(W0, A1, acc[0][1], 0,0,0);
    acc[1][0] = __builtin_amdgcn_mfma_f32_32x32x16_bf16(W1, A0, acc[1][0], 0,0,0);
    acc[1][1] = __builtin_amdgcn_mfma_f32_32x32x16_bf16(W1, A1, acc[1][1], 0,0,0);
  }

  if (y < 12){
    // RoPE epilogue (q: scale-fold; k: scale 1). Pairs in-lane.
    const float scale = (y < 6) ? 0.125f*LOG2E : 1.0f;
    bf16_t* dst = (y < 6) ? qh : kh;
#pragma unroll
    for (int rt=0;rt<2;rt++){
      int row = (rt0+rt)*32 + lq;
      float p0 = (float)pos[row*2+0], p1 = (float)pos[row*2+1];
      int bb = row >> 10;
      int tile = (row & 1023) >> 5;
#pragma unroll
      for (int nt=0;nt<2;nt++){
        int ntg = ntbase + nt;
#pragma unroll
        for (int rp=0;rp<8;rp++){
          int r = rp*2;                       // r&3 in {0,2} -> crow(r+1) = crow(r)+1
          int n = ntg*32 + (r&3) + 8*(r>>2) + 4*hi;
          int h = n >> 6, d = n & 63, f = d >> 1;
          float F1 = freqs[h*32 + f];
          float F2 = freqs[H_*32 + h*32 + f];
          float ang = p0*F1 + p1*F2;
          float sn, cs;
          __sincosf(ang, &sn, &cs);
          float ve = acc[nt][rt][r]   + bias[n];
          float vo = acc[nt][rt][r+1] + bias[n+1];
          float oe = (ve*cs - vo*sn)*scale;
          float oo = (ve*sn + vo*cs)*scale;
          int cc = d >> 4, hi2 = (d >> 3) & 1, jj = d & 7;   // d even -> jj even
          size_t base = ((size_t)((bb*H_ + h)*32 + tile))*2048 + cc*512 + hi2*256 + lq*8 + jj;
          ushort2 o; o.x = bf16b(oe); o.y = bf16b(oo);
          *reinterpret_cast<ushort2*>(dst + base) = o;
        }
      }
    }
  } else {
    // V epilogue: transpose into vfrag (unchanged attn B-operand layout)
#pragma unroll
    for (int rt=0;rt<2;rt++){
      int s_ = (rt0+rt)*32 + lq;             // key row
      int bb = s_ >> 10;
      int kb = (s_ & 1023) >> 5;
      int ks = (lq >> 4) & 1, hi2 = (lq >> 3) & 1, jj = lq & 7;
#pragma unroll
      for (int nt=0;nt<2;nt++){
        int ntg = ntbase + nt;
#pragma unroll
        for (int r=0;r<16;r++){
          int n = ntg*32 + (r&3) + 8*(r>>2) + 4*hi;   // col in kv N-space (>= 768 here)
          int nv = n - D_;
          int h = nv >> 6, d = nv & 63;
          float v = acc[nt][rt][r] + bias[n];
          size_t addr = ((size_t)((bb*H_ + h)*32 + kb))*2048
                      + (d>>5)*1024 + ks*512 + hi2*256 + (d&31)*8 + jj;
          vfrag[addr] = (bf16_t)v;
        }
      }
    }
  }
}

// ---------------- gemm_out: 64x64 dbuf LDS GEMM (R19 form, best measured) ----------------
template<int TM, int TN>
__device__ __forceinline__ void stage_t(const bf16_t* __restrict__ A, const bf16_t* __restrict__ W,
                                        int K, int row0, int col0, int kt,
                                        bf16_t* As, bf16_t* Bs){
  const int tid = threadIdx.x;
  const int wv  = tid >> 6;
#pragma unroll
  for (int i=0;i<TM/32;i++){
    int c = i*256 + tid;
    int r = c >> 3, kc = (c & 7) ^ (r & 7);
    gload16(A + (size_t)(row0+r)*K + kt + kc*8, As + (size_t)(i*256 + wv*64)*8);
  }
#pragma unroll
  for (int i=0;i<TN/32;i++){
    int c = i*256 + tid;
    int r = c >> 3, kc = (c & 7) ^ (r & 7);
    gload16(W + (size_t)(col0+r)*K + kt + kc*8, Bs + (size_t)(i*256 + wv*64)*8);
  }
}

template<int TM, int TN>
__device__ __forceinline__ void compute_t(const bf16_t* As, const bf16_t* Bs,
                                          f32x4 (&acc)[TM/32][TN/32]){
  const int lane = threadIdx.x & 63;
  const int wv   = threadIdx.x >> 6;
  const int wr = wv >> 1, wc = wv & 1;
  const int l4 = lane >> 4, lm = lane & 15;
#pragma unroll
  for (int kk=0; kk<2; kk++){
    bf16x8 af[TM/32], bfr[TN/32];
#pragma unroll
    for (int mi=0;mi<TM/32;mi++){
      int r = wr*(TM/2) + mi*16 + lm;
      int s = (kk*4 + l4) ^ (r & 7);
      af[mi] = *reinterpret_cast<const bf16x8*>(As + r*64 + s*8);
    }
#pragma unroll
    for (int ni=0;ni<TN/32;ni++){
      int r = wc*(TN/2) + ni*16 + lm;
      int s = (kk*4 + l4) ^ (r & 7);
      bfr[ni] = *reinterpret_cast<const bf16x8*>(Bs + r*64 + s*8);
    }
#pragma unroll
    for (int mi=0;mi<TM/32;mi++)
#pragma unroll
      for (int ni=0;ni<TN/32;ni++)
        acc[mi][ni] = __builtin_amdgcn_mfma_f32_16x16x32_bf16(af[mi], bfr[ni], acc[mi][ni], 0,0,0);
  }
}

__global__ void gemm_kernel(const bf16_t* __restrict__ A, const bf16_t* __restrict__ W,
                            const float* __restrict__ bias, float* __restrict__ C,
                            int N, int K){
  __shared__ bf16_t As[2][64*64];
  __shared__ bf16_t Bs[2][64*64];
  int l = ((int)blockIdx.x & 7)*96 + ((int)blockIdx.x >> 3);
  int x = l & 63, y = l >> 6;       // 64 row tiles x 12 col tiles
  f32x4 acc[2][2] = {};
  stage_t<64,64>(A, W, K, x*64, y*64, 0, As[0], Bs[0]);
  __syncthreads();
  const int nt = K/64;
  for (int t=0; t<nt; ++t){
    int cur = t & 1;
    if (t+1 < nt)
      stage_t<64,64>(A, W, K, x*64, y*64, (t+1)*64, As[cur^1], Bs[cur^1]);
    compute_t<64,64>(As[cur], Bs[cur], acc);
    __syncthreads();
  }
  const int lane = threadIdx.x & 63;
  const int wv   = threadIdx.x >> 6;
  const int wr = wv >> 1, wc = wv & 1;
  const int l4 = lane >> 4, lm = lane & 15;
  const int row0 = x*64, col0 = y*64;
#pragma unroll
  for (int mi=0;mi<2;mi++){
#pragma unroll
    for (int ni=0;ni<2;ni++){
      int col = col0 + wc*32 + ni*16 + lm;
      float bv = bias[col];
#pragma unroll
      for (int j=0;j<4;j++){
        int row = row0 + wr*32 + mi*16 + l4*4 + j;
        C[(size_t)row*N + col] = acc[mi][ni][j] + bv;
      }
    }
  }
}

// ---------------- one attention step: QK^T -> exp2 -> P repack -> PV ----------------
__device__ __forceinline__ void attn_step(const bf16x8 (&kf)[4], const bf16x8 (&vf)[4],
                                          const bf16x8 (&qf)[4], f32x16 (&acc_o)[2],
                                          float &psum){
  f32x16 accs = {};
#pragma unroll
  for (int c=0;c<4;c++)
    accs = __builtin_amdgcn_mfma_f32_32x32x16_bf16(kf[c], qf[c], accs, 0,0,0);
#pragma unroll
  for (int r=0;r<16;r++){
    float v = exp2f(accs[r]);
    accs[r] = v;
    psum += v;
  }
  bf16x8 pa[2];
#pragma unroll
  for (int ks=0;ks<2;ks++){
    const int base = ks*8;
    unsigned int a0 = cvtpk(accs[base+0], accs[base+1]);
    unsigned int a1 = cvtpk(accs[base+2], accs[base+3]);
    unsigned int b0 = cvtpk(accs[base+4], accs[base+5]);
    unsigned int b1 = cvtpk(accs[base+6], accs[base+7]);
    plswap(a0, b0);
    plswap(a1, b1);
    u32x4 w; w[0]=a0; w[1]=a1; w[2]=b0; w[3]=b1;
    pa[ks] = __builtin_bit_cast(bf16x8, w);
  }
#pragma unroll
  for (int dt=0;dt<2;dt++)
#pragma unroll
    for (int ks=0;ks<2;ks++)
      acc_o[dt] = __builtin_amdgcn_mfma_f32_32x32x16_bf16(pa[ks], vf[dt*2+ks], acc_o[dt], 0,0,0);
}

// ---------------- flash attention (R13 kernel, unchanged) ----------------
__global__ __launch_bounds__(256, 3)
void attn_kernel(const bf16_t* __restrict__ Qf, const bf16_t* __restrict__ Kf,
                 const bf16_t* __restrict__ Vf, bf16_t* __restrict__ Oh){
  const int lane = threadIdx.x & 63;
  const int wv   = threadIdx.x >> 6;  // key-quarter 0..3
  const int hi = lane >> 5, lq = lane & 31;
  int l = ((int)blockIdx.x & 7)*192 + ((int)blockIdx.x >> 3);
  const int bh = l >> 5;
  const int qt = l & 31;
  const int q0 = qt*32;
  const int b = bh / H_, h = bh % H_;
  const size_t headoff = ((size_t)b*S_*H_ + h)*HD_;

  __shared__ float part[4][64][33];
  __shared__ float ps[4][32];

  bf16x8 qf[4];
  {
    const bf16_t* qp_ = Qf + (size_t)(bh*32 + qt)*2048 + lane*8;
#pragma unroll
    for (int c=0;c<4;c++)
      qf[c] = *reinterpret_cast<const bf16x8*>(qp_ + c*512);
  }

  const bf16_t* kbase = Kf + ((size_t)bh*32 + wv*8)*2048 + lane*8;
  const bf16_t* vbase = Vf + ((size_t)bh*32 + wv*8)*2048 + lane*8;

  float psum = 0.f;
  f32x16 acc_o[2] = {};

  bf16x8 kfA[4], kfB[4], vf[4];
#pragma unroll
  for (int c=0;c<4;c++)
    kfA[c] = *reinterpret_cast<const bf16x8*>(kbase + c*512);

#pragma unroll
  for (int t=0; t<4; ++t){
    {
      const bf16_t* vp = vbase + (size_t)(2*t)*2048;
#pragma unroll
      for (int j=0;j<4;j++) vf[j] = *reinterpret_cast<const bf16x8*>(vp + j*512);
      const bf16_t* kp = kbase + (size_t)(2*t+1)*2048;
#pragma unroll
      for (int c=0;c<4;c++) kfB[c] = *reinterpret_cast<const bf16x8*>(kp + c*512);
      attn_step(kfA, vf, qf, acc_o, psum);
    }
    {
      const bf16_t* vp = vbase + (size_t)(2*t+1)*2048;
#pragma unroll
      for (int j=0;j<4;j++) vf[j] = *reinterpret_cast<const bf16x8*>(vp + j*512);
      if (t < 3){
        const bf16_t* kp = kbase + (size_t)(2*t+2)*2048;
#pragma unroll
        for (int c=0;c<4;c++) kfA[c] = *reinterpret_cast<const bf16x8*>(kp + c*512);
      }
      attn_step(kfB, vf, qf, acc_o, psum);
    }
  }

  float tp = psum + __shfl_xor(psum, 32, 64);
#pragma unroll
  for (int dt=0;dt<2;dt++)
#pragma unroll
    for (int r=0;r<16;r++)
      part[wv][lane][dt*16+r] = acc_o[dt][r];
  if (lane < 32) ps[wv][lq] = tp;
  __syncthreads();

  const int dt = wv >> 1;
  const int rbase = (wv & 1)*8;
  float tot = ps[0][lq] + ps[1][lq] + ps[2][lq] + ps[3][lq];
  float inv = 1.0f / tot;

  bf16_t* obase = Oh + headoff;
#pragma unroll
  for (int ri=0;ri<8;ri++){
    int r = rbase + ri;
    float s = part[0][lane][dt*16+r] + part[1][lane][dt*16+r]
            + part[2][lane][dt*16+r] + part[3][lane][dt*16+r];
    float invr = __shfl(inv, (r&3) + 8*(r>>2) + 4*hi, 64);
    int qq = q0 + (r&3) + 8*(r>>2) + 4*hi;
    obase[(size_t)qq*RSTRIDE + dt*32 + lq] = (bf16_t)(s*invr);
  }
}

// ---------------- launch ----------------
extern "C" void kernel_launch(void* const* d_in, const int* in_sizes, int n_in,
                              void* d_out, int out_size, void* d_ws, size_t ws_size,
                              hipStream_t stream) {
  const float* q      = (const float*)d_in[0];
  const float* kv     = (const float*)d_in[1];
  const int*   posq   = (const int*)d_in[2];
  const int*   posk   = (const int*)d_in[3];
  const float* w_norm = (const float*)d_in[4];
  const float* w_q    = (const float*)d_in[5];
  const float* b_q    = (const float*)d_in[6];
  const float* w_kv   = (const float*)d_in[7];
  const float* b_kv   = (const float*)d_in[8];
  const float* w_out  = (const float*)d_in[9];
  const float* b_out  = (const float*)d_in[10];
  const float* freqs  = (const float*)d_in[11];
  float* out = (float*)d_out;

  char* p = (char*)d_ws;
  bf16_t* qnf  = (bf16_t*)p; p += (size_t)NROW*D_*2;    // q rmsnorm, frag48
  bf16_t* kvbf = (bf16_t*)p; p += (size_t)NROW*D_*2;    // kv cast, frag48
  bf16_t* wqf  = (bf16_t*)p; p += (size_t)D_*D_*2;      // w_q, frag48
  bf16_t* wkvf = (bf16_t*)p; p += (size_t)2*D_*D_*2;    // w_kv, frag48
  bf16_t* wob  = (bf16_t*)p; p += (size_t)D_*D_*2;      // w_out, row-major
  bf16_t* qh   = (bf16_t*)p; p += (size_t)NROW*D_*2;    // Q fragments
  bf16_t* kh   = (bf16_t*)p; p += (size_t)NROW*D_*2;    // K fragments
  bf16_t* vt   = (bf16_t*)p; p += (size_t)NBH*HD_*S_*2; // V fragments
  bf16_t* oh   = (bf16_t*)p; p += (size_t)NROW*D_*2;

  // 1) RMSNorm + casts into fragment layouts
  prep_kernel<<<NROW + 5376, 256, 0, stream>>>(q, w_norm, qnf,
                                               w_q, wqf, w_kv, wkvf, w_out, wob, kv, kvbf);
  // 2) q/kv projection: no-LDS fragment-streaming GEMM + fused RoPE/V-pack
  gemm_qkv_kernel<<<576, 256, 0, stream>>>(qnf, kvbf, wqf, wkvf, b_q, b_kv,
                                           posq, posk, freqs, qh, kh, vt);
  // 3) attention (R13 kernel)
  attn_kernel<<<1536, 256, 0, stream>>>(qh, kh, vt, oh);
  // 4) output projection (64x64 dbuf) -> f32 d_out
  gemm_kernel<<<768, 256, 0, stream>>>(oh, wob, b_out, out, D_, D_);
}

// Round 22
// 77.749 us; speedup vs baseline: 1.1558x; 1.1558x over previous
//
#include <hip/hip_runtime.h>

#define B_   4
#define S_   1024
#define D_   768
#define H_   12
#define HD_  64
#define NROW (B_*S_)          // 4096
#define RSTRIDE (H_*HD_)      // 768
#define NBH  (B_*H_)          // 48
#define LOG2E 1.44269504f

typedef __bf16 bf16_t;
typedef bf16_t bf16x8 __attribute__((ext_vector_type(8)));
typedef float  f32x4  __attribute__((ext_vector_type(4)));
typedef float  f32x16 __attribute__((ext_vector_type(16)));
typedef unsigned int u32x4 __attribute__((ext_vector_type(4)));

__device__ __forceinline__ unsigned short bf16b(float f){
  bf16_t b = (bf16_t)f;
  return __builtin_bit_cast(unsigned short, b);
}

__device__ __forceinline__ void gload16(const void* g, void* l){
  __builtin_amdgcn_global_load_lds(
      (const __attribute__((address_space(1))) void*)g,
      (__attribute__((address_space(3))) void*)l, 16, 0, 0);
}

__device__ __forceinline__ unsigned int cvtpk(float lo, float hi){
  unsigned int r;
  asm("v_cvt_pk_bf16_f32 %0, %1, %2" : "=v"(r) : "v"(lo), "v"(hi));
  return r;
}

__device__ __forceinline__ void plswap(unsigned int &a, unsigned int &b){
  asm volatile("v_permlane32_swap_b32 %0, %1" : "+v"(a), "+v"(b));
}

// ---------------- fused prep: RMSNorm(q) + all f32->bf16 casts, one launch ----------------
__global__ void prep_kernel(const float* __restrict__ q, const float* __restrict__ w_norm,
                            bf16_t* __restrict__ qn,
                            const float* __restrict__ wq,  bf16_t* __restrict__ wqb,
                            const float* __restrict__ wkv, bf16_t* __restrict__ wkvb,
                            const float* __restrict__ wo,  bf16_t* __restrict__ wob,
                            const float* __restrict__ kv,  bf16_t* __restrict__ kvb){
  int bid = blockIdx.x;
  if (bid < NROW){
    int row = bid;
    const float* src = q + (size_t)row*D_;
    float vals[3]; float ss = 0.f;
#pragma unroll
    for (int i=0;i<3;i++){ float v = src[threadIdx.x + i*256]; vals[i]=v; ss += v*v; }
#pragma unroll
    for (int m=1;m<64;m<<=1) ss += __shfl_xor(ss, m, 64);
    __shared__ float red[4];
    if ((threadIdx.x & 63) == 0) red[threadIdx.x>>6] = ss;
    __syncthreads();
    float tot = red[0]+red[1]+red[2]+red[3];
    float rs = rsqrtf(tot*(1.0f/D_) + 1e-5f);
#pragma unroll
    for (int i=0;i<3;i++){
      int c = threadIdx.x + i*256;
      qn[(size_t)row*D_ + c] = (bf16_t)(vals[i]*rs*w_norm[c]);
    }
  } else {
    int i = (bid - NROW)*256 + threadIdx.x;
    const int n0 = D_*D_/4, n1 = 2*D_*D_/4, n2 = D_*D_/4, n3 = NROW*D_/4;
    const float* s; bf16_t* d; int off;
    if (i < n0){ s = wq; d = wqb; off = i; }
    else if (i < n0+n1){ s = wkv; d = wkvb; off = i - n0; }
    else if (i < n0+n1+n2){ s = wo; d = wob; off = i - n0 - n1; }
    else if (i < n0+n1+n2+n3){ s = kv; d = kvb; off = i - n0 - n1 - n2; }
    else return;
    float4 v = reinterpret_cast<const float4*>(s)[off];
    ushort4 o;
    o.x = bf16b(v.x); o.y = bf16b(v.y); o.z = bf16b(v.z); o.w = bf16b(v.w);
    reinterpret_cast<ushort4*>(d)[off] = o;
  }
}

// ---------------- BK=128 single-buffer stage/compute (gemm_qkv) ----------------
// LDS rows of 128 elems = 16 slots of 16B. Swizzle: slot = ((c&7)^(r&7)) | (c&8)
// (involution; preserves bit3). Source pre-swizzled, dest linear, read swizzled.
template<int TM, int TN>
__device__ __forceinline__ void stage128(const bf16_t* __restrict__ A, const bf16_t* __restrict__ W,
                                         int K, int row0, int col0, int kt,
                                         bf16_t* As, bf16_t* Bs){
  const int tid = threadIdx.x;
  const int wv  = tid >> 6;
#pragma unroll
  for (int i=0;i<TM/16;i++){
    int c = i*256 + tid;
    int r = c >> 4, sl = c & 15;
    int kc = ((sl & 7) ^ (r & 7)) | (sl & 8);
    gload16(A + (size_t)(row0+r)*K + kt + kc*8, As + (size_t)(i*256 + wv*64)*8);
  }
#pragma unroll
  for (int i=0;i<TN/16;i++){
    int c = i*256 + tid;
    int r = c >> 4, sl = c & 15;
    int kc = ((sl & 7) ^ (r & 7)) | (sl & 8);
    gload16(W + (size_t)(col0+r)*K + kt + kc*8, Bs + (size_t)(i*256 + wv*64)*8);
  }
}

template<int TM, int TN>
__device__ __forceinline__ void compute128(const bf16_t* As, const bf16_t* Bs,
                                           f32x4 (&acc)[TM/32][TN/32]){
  const int lane = threadIdx.x & 63;
  const int wv   = threadIdx.x >> 6;
  const int wr = wv >> 1, wc = wv & 1;
  const int l4 = lane >> 4, lm = lane & 15;
#pragma unroll
  for (int kk=0; kk<4; kk++){
    bf16x8 af[TM/32], bfr[TN/32];
#pragma unroll
    for (int mi=0;mi<TM/32;mi++){
      int r = wr*(TM/2) + mi*16 + lm;
      int t = kk*4 + l4;
      int s = ((t & 7) ^ (r & 7)) | (t & 8);
      af[mi] = *reinterpret_cast<const bf16x8*>(As + r*128 + s*8);
    }
#pragma unroll
    for (int ni=0;ni<TN/32;ni++){
      int r = wc*(TN/2) + ni*16 + lm;
      int t = kk*4 + l4;
      int s = ((t & 7) ^ (r & 7)) | (t & 8);
      bfr[ni] = *reinterpret_cast<const bf16x8*>(Bs + r*128 + s*8);
    }
#pragma unroll
    for (int mi=0;mi<TM/32;mi++)
#pragma unroll
      for (int ni=0;ni<TN/32;ni++)
        acc[mi][ni] = __builtin_amdgcn_mfma_f32_16x16x32_bf16(af[mi], bfr[ni], acc[mi][ni], 0,0,0);
  }
}

// ---------------- BK=64 dbuf blocks (gemm_out; R19 best-measured form) ----------------
template<int TM, int TN>
__device__ __forceinline__ void stage_t(const bf16_t* __restrict__ A, const bf16_t* __restrict__ W,
                                        int K, int row0, int col0, int kt,
                                        bf16_t* As, bf16_t* Bs){
  const int tid = threadIdx.x;
  const int wv  = tid >> 6;
#pragma unroll
  for (int i=0;i<TM/32;i++){
    int c = i*256 + tid;
    int r = c >> 3, kc = (c & 7) ^ (r & 7);
    gload16(A + (size_t)(row0+r)*K + kt + kc*8, As + (size_t)(i*256 + wv*64)*8);
  }
#pragma unroll
  for (int i=0;i<TN/32;i++){
    int c = i*256 + tid;
    int r = c >> 3, kc = (c & 7) ^ (r & 7);
    gload16(W + (size_t)(col0+r)*K + kt + kc*8, Bs + (size_t)(i*256 + wv*64)*8);
  }
}

template<int TM, int TN>
__device__ __forceinline__ void compute_t(const bf16_t* As, const bf16_t* Bs,
                                          f32x4 (&acc)[TM/32][TN/32]){
  const int lane = threadIdx.x & 63;
  const int wv   = threadIdx.x >> 6;
  const int wr = wv >> 1, wc = wv & 1;
  const int l4 = lane >> 4, lm = lane & 15;
#pragma unroll
  for (int kk=0; kk<2; kk++){
    bf16x8 af[TM/32], bfr[TN/32];
#pragma unroll
    for (int mi=0;mi<TM/32;mi++){
      int r = wr*(TM/2) + mi*16 + lm;
      int s = (kk*4 + l4) ^ (r & 7);
      af[mi] = *reinterpret_cast<const bf16x8*>(As + r*64 + s*8);
    }
#pragma unroll
    for (int ni=0;ni<TN/32;ni++){
      int r = wc*(TN/2) + ni*16 + lm;
      int s = (kk*4 + l4) ^ (r & 7);
      bfr[ni] = *reinterpret_cast<const bf16x8*>(Bs + r*64 + s*8);
    }
#pragma unroll
    for (int mi=0;mi<TM/32;mi++)
#pragma unroll
      for (int ni=0;ni<TN/32;ni++)
        acc[mi][ni] = __builtin_amdgcn_mfma_f32_16x16x32_bf16(af[mi], bfr[ni], acc[mi][ni], 0,0,0);
  }
}

__global__ void gemm_kernel(const bf16_t* __restrict__ A, const bf16_t* __restrict__ W,
                            const float* __restrict__ bias, float* __restrict__ C,
                            int N, int K){
  __shared__ bf16_t As[2][64*64];
  __shared__ bf16_t Bs[2][64*64];
  int l = ((int)blockIdx.x & 7)*96 + ((int)blockIdx.x >> 3);
  int x = l & 63, y = l >> 6;       // 64 row tiles x 12 col tiles
  f32x4 acc[2][2] = {};
  stage_t<64,64>(A, W, K, x*64, y*64, 0, As[0], Bs[0]);
  __syncthreads();
  const int nt = K/64;
  for (int t=0; t<nt; ++t){
    int cur = t & 1;
    if (t+1 < nt)
      stage_t<64,64>(A, W, K, x*64, y*64, (t+1)*64, As[cur^1], Bs[cur^1]);
    compute_t<64,64>(As[cur], Bs[cur], acc);
    __syncthreads();
  }
  const int lane = threadIdx.x & 63;
  const int wv   = threadIdx.x >> 6;
  const int wr = wv >> 1, wc = wv & 1;
  const int l4 = lane >> 4, lm = lane & 15;
  const int row0 = x*64, col0 = y*64;
#pragma unroll
  for (int mi=0;mi<2;mi++){
#pragma unroll
    for (int ni=0;ni<2;ni++){
      int col = col0 + wc*32 + ni*16 + lm;
      float bv = bias[col];
#pragma unroll
      for (int j=0;j<4;j++){
        int row = row0 + wr*32 + mi*16 + l4*4 + j;
        C[(size_t)row*N + col] = acc[mi][ni][j] + bv;
      }
    }
  }
}

// ---------------- fused epilogue: bias + RoPE + fragment-pack (q or k), TM=64/TN=128 ----------------
__device__ __forceinline__ void epi_rope(f32x4 (&acc)[2][4], const float* __restrict__ bias,
                                         const int* __restrict__ pos, const float* __restrict__ freqs,
                                         bf16_t* __restrict__ dst, int row0, int col0, float scale){
  const int lane = threadIdx.x & 63;
  const int wv   = threadIdx.x >> 6;
  const int wr = wv >> 1, wc = wv & 1;
  const int l4 = lane >> 4, lm = lane & 15;
  const int par = lm & 1;
#pragma unroll
  for (int ni=0;ni<4;ni++){
    int col = col0 + wc*64 + ni*16 + lm;
    int h = col >> 6, hd = col & 63, f = hd >> 1;
    float F1 = freqs[h*32 + f];
    float F2 = freqs[H_*32 + h*32 + f];
    float bv = bias[col];
    int cc = f >> 3, hi = (f >> 2) & 1;
    int ebase = cc*512 + hi*256 + (f&3)*2 + par;
#pragma unroll
    for (int mi=0;mi<2;mi++){
#pragma unroll
      for (int j=0;j<4;j++){
        int row = row0 + wr*32 + mi*16 + l4*4 + j;
        float v = acc[mi][ni][j] + bv;
        float vp = __shfl_xor(v, 1, 64);
        float p0 = (float)pos[row*2+0], p1 = (float)pos[row*2+1];
        float ang = p0*F1 + p1*F2;
        float sn, cs;
        __sincosf(ang, &sn, &cs);
        float out = (par ? (vp*sn + v*cs) : (v*cs - vp*sn)) * scale;
        int b = row >> 10, s = row & 1023;
        int bh = b*H_ + h, tile = s >> 5, lq = s & 31;
        dst[((size_t)(bh*32 + tile))*2048 + ebase + lq*8] = (bf16_t)out;
      }
    }
  }
}

// ---------------- fused epilogue: bias + V fragment-pack (transpose), TM=64/TN=128 ----------------
__device__ __forceinline__ void epi_vpack(f32x4 (&acc)[2][4], const float* __restrict__ bias,
                                          bf16_t* __restrict__ vfrag, int row0, int col0){
  const int lane = threadIdx.x & 63;
  const int wv   = threadIdx.x >> 6;
  const int wr = wv >> 1, wc = wv & 1;
  const int l4 = lane >> 4, lm = lane & 15;
#pragma unroll
  for (int ni=0;ni<4;ni++){
    int col = col0 + wc*64 + ni*16 + lm;
    int vcol = col - D_;
    int h = vcol >> 6, d = vcol & 63;
    int dt = d >> 5, lq2 = d & 31;
    float bv = bias[col];
    int ebase = dt*1024 + lq2*8;
#pragma unroll
    for (int mi=0;mi<2;mi++){
#pragma unroll
      for (int j=0;j<4;j++){
        int row = row0 + wr*32 + mi*16 + l4*4 + j;
        int b = row >> 10, s = row & 1023;
        int bh = b*H_ + h;
        int kb = s >> 5, ks = (s >> 4) & 1, hi2 = (s >> 3) & 1, jj = s & 7;
        vfrag[((size_t)(bh*32 + kb))*2048 + ebase + ks*512 + hi2*256 + jj]
            = (bf16_t)(acc[mi][ni][j] + bv);
      }
    }
  }
}

// ---------------- fused q-proj + kv-proj + RoPE + pack: 64x128 tiles, BK=128, 1152 blocks ----------------
// 6 K-iterations (vs 12 at BK=64): halves the per-iteration latency exposures,
// the one knob that has measurably moved this kernel (R16: BK 32->64 gave -5.8us).
__global__ void gemm_qkv_kernel(const bf16_t* __restrict__ qn, const bf16_t* __restrict__ kvb,
                                const bf16_t* __restrict__ wq, const bf16_t* __restrict__ wkv,
                                const float* __restrict__ bq, const float* __restrict__ bkv,
                                const int* __restrict__ posq, const int* __restrict__ posk,
                                const float* __restrict__ freqs,
                                bf16_t* __restrict__ qh, bf16_t* __restrict__ kh,
                                bf16_t* __restrict__ vfrag){
  __shared__ bf16_t As[64*128];    // 16 KB
  __shared__ bf16_t Bs[128*128];   // 32 KB
  int l = ((int)blockIdx.x & 7)*144 + ((int)blockIdx.x >> 3);
  int x = l & 63, y = l >> 6;       // x: 64 row tiles (64 rows), y: 18 col tiles (128 cols)
  f32x4 acc[2][4] = {};
  const bf16_t* A; const bf16_t* W; int c0;
  if (y < 6){ A = qn;  W = wq;  c0 = y*128; }
  else      { A = kvb; W = wkv; c0 = (y-6)*128; }

  for (int kt = 0; kt < D_; kt += 128){
    stage128<64,128>(A, W, D_, x*64, c0, kt, As, Bs);
    __syncthreads();
    compute128<64,128>(As, Bs, acc);
    __syncthreads();
  }

  if (y < 6)
    epi_rope(acc, bq, posq, freqs, qh, x*64, c0, 0.125f*LOG2E);
  else if (y < 12)
    epi_rope(acc, bkv, posk, freqs, kh, x*64, c0, 1.0f);
  else
    epi_vpack(acc, bkv, vfrag, x*64, c0);
}

// ---------------- one attention step: QK^T -> exp2 -> P repack -> PV ----------------
__device__ __forceinline__ void attn_step(const bf16x8 (&kf)[4], const bf16x8 (&vf)[4],
                                          const bf16x8 (&qf)[4], f32x16 (&acc_o)[2],
                                          float &psum){
  f32x16 accs = {};
#pragma unroll
  for (int c=0;c<4;c++)
    accs = __builtin_amdgcn_mfma_f32_32x32x16_bf16(kf[c], qf[c], accs, 0,0,0);
#pragma unroll
  for (int r=0;r<16;r++){
    float v = exp2f(accs[r]);
    accs[r] = v;
    psum += v;
  }
  bf16x8 pa[2];
#pragma unroll
  for (int ks=0;ks<2;ks++){
    const int base = ks*8;
    unsigned int a0 = cvtpk(accs[base+0], accs[base+1]);
    unsigned int a1 = cvtpk(accs[base+2], accs[base+3]);
    unsigned int b0 = cvtpk(accs[base+4], accs[base+5]);
    unsigned int b1 = cvtpk(accs[base+6], accs[base+7]);
    plswap(a0, b0);
    plswap(a1, b1);
    u32x4 w; w[0]=a0; w[1]=a1; w[2]=b0; w[3]=b1;
    pa[ks] = __builtin_bit_cast(bf16x8, w);
  }
#pragma unroll
  for (int dt=0;dt<2;dt++)
#pragma unroll
    for (int ks=0;ks<2;ks++)
      acc_o[dt] = __builtin_amdgcn_mfma_f32_32x32x16_bf16(pa[ks], vf[dt*2+ks], acc_o[dt], 0,0,0);
}

// ---------------- flash attention (R13 kernel, unchanged) ----------------
__global__ __launch_bounds__(256, 3)
void attn_kernel(const bf16_t* __restrict__ Qf, const bf16_t* __restrict__ Kf,
                 const bf16_t* __restrict__ Vf, bf16_t* __restrict__ Oh){
  const int lane = threadIdx.x & 63;
  const int wv   = threadIdx.x >> 6;  // key-quarter 0..3
  const int hi = lane >> 5, lq = lane & 31;
  int l = ((int)blockIdx.x & 7)*192 + ((int)blockIdx.x >> 3);
  const int bh = l >> 5;
  const int qt = l & 31;
  const int q0 = qt*32;
  const int b = bh / H_, h = bh % H_;
  const size_t headoff = ((size_t)b*S_*H_ + h)*HD_;

  __shared__ float part[4][64][33];
  __shared__ float ps[4][32];

  bf16x8 qf[4];
  {
    const bf16_t* qp_ = Qf + (size_t)(bh*32 + qt)*2048 + lane*8;
#pragma unroll
    for (int c=0;c<4;c++)
      qf[c] = *reinterpret_cast<const bf16x8*>(qp_ + c*512);
  }

  const bf16_t* kbase = Kf + ((size_t)bh*32 + wv*8)*2048 + lane*8;
  const bf16_t* vbase = Vf + ((size_t)bh*32 + wv*8)*2048 + lane*8;

  float psum = 0.f;
  f32x16 acc_o[2] = {};

  bf16x8 kfA[4], kfB[4], vf[4];
#pragma unroll
  for (int c=0;c<4;c++)
    kfA[c] = *reinterpret_cast<const bf16x8*>(kbase + c*512);

#pragma unroll
  for (int t=0; t<4; ++t){
    {
      const bf16_t* vp = vbase + (size_t)(2*t)*2048;
#pragma unroll
      for (int j=0;j<4;j++) vf[j] = *reinterpret_cast<const bf16x8*>(vp + j*512);
      const bf16_t* kp = kbase + (size_t)(2*t+1)*2048;
#pragma unroll
      for (int c=0;c<4;c++) kfB[c] = *reinterpret_cast<const bf16x8*>(kp + c*512);
      attn_step(kfA, vf, qf, acc_o, psum);
    }
    {
      const bf16_t* vp = vbase + (size_t)(2*t+1)*2048;
#pragma unroll
      for (int j=0;j<4;j++) vf[j] = *reinterpret_cast<const bf16x8*>(vp + j*512);
      if (t < 3){
        const bf16_t* kp = kbase + (size_t)(2*t+2)*2048;
#pragma unroll
        for (int c=0;c<4;c++) kfA[c] = *reinterpret_cast<const bf16x8*>(kp + c*512);
      }
      attn_step(kfB, vf, qf, acc_o, psum);
    }
  }

  float tp = psum + __shfl_xor(psum, 32, 64);
#pragma unroll
  for (int dt=0;dt<2;dt++)
#pragma unroll
    for (int r=0;r<16;r++)
      part[wv][lane][dt*16+r] = acc_o[dt][r];
  if (lane < 32) ps[wv][lq] = tp;
  __syncthreads();

  const int dt = wv >> 1;
  const int rbase = (wv & 1)*8;
  float tot = ps[0][lq] + ps[1][lq] + ps[2][lq] + ps[3][lq];
  float inv = 1.0f / tot;

  bf16_t* obase = Oh + headoff;
#pragma unroll
  for (int ri=0;ri<8;ri++){
    int r = rbase + ri;
    float s = part[0][lane][dt*16+r] + part[1][lane][dt*16+r]
            + part[2][lane][dt*16+r] + part[3][lane][dt*16+r];
    float invr = __shfl(inv, (r&3) + 8*(r>>2) + 4*hi, 64);
    int qq = q0 + (r&3) + 8*(r>>2) + 4*hi;
    obase[(size_t)qq*RSTRIDE + dt*32 + lq] = (bf16_t)(s*invr);
  }
}

// ---------------- launch ----------------
extern "C" void kernel_launch(void* const* d_in, const int* in_sizes, int n_in,
                              void* d_out, int out_size, void* d_ws, size_t ws_size,
                              hipStream_t stream) {
  const float* q      = (const float*)d_in[0];
  const float* kv     = (const float*)d_in[1];
  const int*   posq   = (const int*)d_in[2];
  const int*   posk   = (const int*)d_in[3];
  const float* w_norm = (const float*)d_in[4];
  const float* w_q    = (const float*)d_in[5];
  const float* b_q    = (const float*)d_in[6];
  const float* w_kv   = (const float*)d_in[7];
  const float* b_kv   = (const float*)d_in[8];
  const float* w_out  = (const float*)d_in[9];
  const float* b_out  = (const float*)d_in[10];
  const float* freqs  = (const float*)d_in[11];
  float* out = (float*)d_out;

  char* p = (char*)d_ws;
  bf16_t* qn   = (bf16_t*)p; p += (size_t)NROW*D_*2;
  bf16_t* kvb  = (bf16_t*)p; p += (size_t)NROW*D_*2;
  bf16_t* wqb  = (bf16_t*)p; p += (size_t)D_*D_*2;
  bf16_t* wkvb = (bf16_t*)p; p += (size_t)2*D_*D_*2;
  bf16_t* wob  = (bf16_t*)p; p += (size_t)D_*D_*2;
  bf16_t* qh   = (bf16_t*)p; p += (size_t)NROW*D_*2;    // Q fragments
  bf16_t* kh   = (bf16_t*)p; p += (size_t)NROW*D_*2;    // K fragments
  bf16_t* vt   = (bf16_t*)p; p += (size_t)NBH*HD_*S_*2; // V fragments
  bf16_t* oh   = (bf16_t*)p; p += (size_t)NROW*D_*2;

  // 1) RMSNorm + all casts
  prep_kernel<<<NROW + 5376, 256, 0, stream>>>(q, w_norm, qn,
                                               w_q, wqb, w_kv, wkvb, w_out, wob, kv, kvb);
  // 2) q-proj + kv-proj GEMM (64x128, BK=128, 6 K-iterations) + fused RoPE/pack epilogues
  gemm_qkv_kernel<<<1152, 256, 0, stream>>>(qn, kvb, wqb, wkvb, b_q, b_kv,
                                            posq, posk, freqs, qh, kh, vt);
  // 3) attention (R13 kernel)
  attn_kernel<<<1536, 256, 0, stream>>>(qh, kh, vt, oh);
  // 4) output projection (64x64, dbuf) -> f32 d_out
  gemm_kernel<<<768, 256, 0, stream>>>(oh, wob, b_out, out, D_, D_);
}

// Round 23
// 77.120 us; speedup vs baseline: 1.1652x; 1.0082x over previous
//
#include <hip/hip_runtime.h>

#define B_   4
#define S_   1024
#define D_   768
#define H_   12
#define HD_  64
#define NROW (B_*S_)          // 4096
#define RSTRIDE (H_*HD_)      // 768
#define NBH  (B_*H_)          // 48
#define LOG2E 1.44269504f

typedef __bf16 bf16_t;
typedef bf16_t bf16x8 __attribute__((ext_vector_type(8)));
typedef float  f32x4  __attribute__((ext_vector_type(4)));
typedef float  f32x16 __attribute__((ext_vector_type(16)));
typedef unsigned int u32x4 __attribute__((ext_vector_type(4)));

__device__ __forceinline__ unsigned short bf16b(float f){
  bf16_t b = (bf16_t)f;
  return __builtin_bit_cast(unsigned short, b);
}

__device__ __forceinline__ void gload16(const void* g, void* l){
  __builtin_amdgcn_global_load_lds(
      (const __attribute__((address_space(1))) void*)g,
      (__attribute__((address_space(3))) void*)l, 16, 0, 0);
}

__device__ __forceinline__ unsigned int cvtpk(float lo, float hi){
  unsigned int r;
  asm("v_cvt_pk_bf16_f32 %0, %1, %2" : "=v"(r) : "v"(lo), "v"(hi));
  return r;
}

__device__ __forceinline__ void plswap(unsigned int &a, unsigned int &b){
  asm volatile("v_permlane32_swap_b32 %0, %1" : "+v"(a), "+v"(b));
}

// ---------------- fused prep: RMSNorm(q) + all f32->bf16 casts, one launch ----------------
__global__ void prep_kernel(const float* __restrict__ q, const float* __restrict__ w_norm,
                            bf16_t* __restrict__ qn,
                            const float* __restrict__ wq,  bf16_t* __restrict__ wqb,
                            const float* __restrict__ wkv, bf16_t* __restrict__ wkvb,
                            const float* __restrict__ wo,  bf16_t* __restrict__ wob,
                            const float* __restrict__ kv,  bf16_t* __restrict__ kvb){
  int bid = blockIdx.x;
  if (bid < NROW){
    int row = bid;
    const float* src = q + (size_t)row*D_;
    float vals[3]; float ss = 0.f;
#pragma unroll
    for (int i=0;i<3;i++){ float v = src[threadIdx.x + i*256]; vals[i]=v; ss += v*v; }
#pragma unroll
    for (int m=1;m<64;m<<=1) ss += __shfl_xor(ss, m, 64);
    __shared__ float red[4];
    if ((threadIdx.x & 63) == 0) red[threadIdx.x>>6] = ss;
    __syncthreads();
    float tot = red[0]+red[1]+red[2]+red[3];
    float rs = rsqrtf(tot*(1.0f/D_) + 1e-5f);
#pragma unroll
    for (int i=0;i<3;i++){
      int c = threadIdx.x + i*256;
      qn[(size_t)row*D_ + c] = (bf16_t)(vals[i]*rs*w_norm[c]);
    }
  } else {
    int i = (bid - NROW)*256 + threadIdx.x;
    const int n0 = D_*D_/4, n1 = 2*D_*D_/4, n2 = D_*D_/4, n3 = NROW*D_/4;
    const float* s; bf16_t* d; int off;
    if (i < n0){ s = wq; d = wqb; off = i; }
    else if (i < n0+n1){ s = wkv; d = wkvb; off = i - n0; }
    else if (i < n0+n1+n2){ s = wo; d = wob; off = i - n0 - n1; }
    else if (i < n0+n1+n2+n3){ s = kv; d = kvb; off = i - n0 - n1 - n2; }
    else return;
    float4 v = reinterpret_cast<const float4*>(s)[off];
    ushort4 o;
    o.x = bf16b(v.x); o.y = bf16b(v.y); o.z = bf16b(v.z); o.w = bf16b(v.w);
    reinterpret_cast<ushort4*>(d)[off] = o;
  }
}

// ---------------- GEMM building blocks: BK=64 swizzled, 256 thr, 2x2 waves ----------------
template<int TM, int TN>
__device__ __forceinline__ void stage_t(const bf16_t* __restrict__ A, const bf16_t* __restrict__ W,
                                        int K, int row0, int col0, int kt,
                                        bf16_t* As, bf16_t* Bs){
  const int tid = threadIdx.x;
  const int wv  = tid >> 6;
#pragma unroll
  for (int i=0;i<TM/32;i++){
    int c = i*256 + tid;
    int r = c >> 3, kc = (c & 7) ^ (r & 7);
    gload16(A + (size_t)(row0+r)*K + kt + kc*8, As + (size_t)(i*256 + wv*64)*8);
  }
#pragma unroll
  for (int i=0;i<TN/32;i++){
    int c = i*256 + tid;
    int r = c >> 3, kc = (c & 7) ^ (r & 7);
    gload16(W + (size_t)(col0+r)*K + kt + kc*8, Bs + (size_t)(i*256 + wv*64)*8);
  }
}

template<int TM, int TN>
__device__ __forceinline__ void compute_t(const bf16_t* As, const bf16_t* Bs,
                                          f32x4 (&acc)[TM/32][TN/32]){
  const int lane = threadIdx.x & 63;
  const int wv   = threadIdx.x >> 6;
  const int wr = wv >> 1, wc = wv & 1;
  const int l4 = lane >> 4, lm = lane & 15;
#pragma unroll
  for (int kk=0; kk<2; kk++){
    bf16x8 af[TM/32], bfr[TN/32];
#pragma unroll
    for (int mi=0;mi<TM/32;mi++){
      int r = wr*(TM/2) + mi*16 + lm;
      int s = (kk*4 + l4) ^ (r & 7);
      af[mi] = *reinterpret_cast<const bf16x8*>(As + r*64 + s*8);
    }
#pragma unroll
    for (int ni=0;ni<TN/32;ni++){
      int r = wc*(TN/2) + ni*16 + lm;
      int s = (kk*4 + l4) ^ (r & 7);
      bfr[ni] = *reinterpret_cast<const bf16x8*>(Bs + r*64 + s*8);
    }
#pragma unroll
    for (int mi=0;mi<TM/32;mi++)
#pragma unroll
      for (int ni=0;ni<TN/32;ni++)
        acc[mi][ni] = __builtin_amdgcn_mfma_f32_16x16x32_bf16(af[mi], bfr[ni], acc[mi][ni], 0,0,0);
  }
}

// Double-buffered core (R19 best-measured form): stage(t+1) issued before compute(t),
// single __syncthreads per tile.
template<int TM, int TN>
__device__ __forceinline__ void gemm_core_db(const bf16_t* __restrict__ A, const bf16_t* __restrict__ W,
                                             int K, int row0, int col0,
                                             bf16_t* As0, bf16_t* As1, bf16_t* Bs0, bf16_t* Bs1,
                                             f32x4 (&acc)[TM/32][TN/32]){
  stage_t<TM,TN>(A, W, K, row0, col0, 0, As0, Bs0);
  __syncthreads();
  const int nt = K/64;
  bf16_t *Ac = As0, *An = As1, *Bc = Bs0, *Bn = Bs1;
  for (int t=0; t<nt; ++t){
    if (t+1 < nt)
      stage_t<TM,TN>(A, W, K, row0, col0, (t+1)*64, An, Bn);
    compute_t<TM,TN>(Ac, Bc, acc);
    __syncthreads();
    bf16_t* tmp;
    tmp = Ac; Ac = An; An = tmp;
    tmp = Bc; Bc = Bn; Bn = tmp;
  }
}

// ---------------- out-proj: 64x64 tiles, dbuf (768 blocks), bias + f32 write ----------------
__global__ void gemm_kernel(const bf16_t* __restrict__ A, const bf16_t* __restrict__ W,
                            const float* __restrict__ bias, float* __restrict__ C,
                            int N, int K){
  __shared__ bf16_t As[2][64*64];
  __shared__ bf16_t Bs[2][64*64];
  int l = ((int)blockIdx.x & 7)*96 + ((int)blockIdx.x >> 3);
  int x = l & 63, y = l >> 6;       // 64 row tiles x 12 col tiles
  f32x4 acc[2][2] = {};
  gemm_core_db<64,64>(A, W, K, x*64, y*64, As[0], As[1], Bs[0], Bs[1], acc);
  const int lane = threadIdx.x & 63;
  const int wv   = threadIdx.x >> 6;
  const int wr = wv >> 1, wc = wv & 1;
  const int l4 = lane >> 4, lm = lane & 15;
  const int row0 = x*64, col0 = y*64;
#pragma unroll
  for (int mi=0;mi<2;mi++){
#pragma unroll
    for (int ni=0;ni<2;ni++){
      int col = col0 + wc*32 + ni*16 + lm;
      float bv = bias[col];
#pragma unroll
      for (int j=0;j<4;j++){
        int row = row0 + wr*32 + mi*16 + l4*4 + j;
        C[(size_t)row*N + col] = acc[mi][ni][j] + bv;
      }
    }
  }
}

// ---------------- fused q-proj + kv-proj + RoPE/V-pack with LDS-STAGED epilogue ----------------
// 64x128 tiles, BK=64 dbuf, 1152 blocks. After the K loop the epilogue writes its
// scattered fragments into a 16KB LDS stage laid out as the 4 destination 4KB chunks
// (hsel=wc, tilesel/kbsel=wr; in-chunk offsets depend only on in-block indices),
// then copies each chunk with fully-coalesced 16B/thread stores. This replaces
// ~32-64 scattered global store instrs/thread (~32 cache lines each) with 4 coalesced.
__global__ void gemm_qkv_kernel(const bf16_t* __restrict__ qn, const bf16_t* __restrict__ kvb,
                                const bf16_t* __restrict__ wq, const bf16_t* __restrict__ wkv,
                                const float* __restrict__ bq, const float* __restrict__ bkv,
                                const int* __restrict__ posq, const int* __restrict__ posk,
                                const float* __restrict__ freqs,
                                bf16_t* __restrict__ qh, bf16_t* __restrict__ kh,
                                bf16_t* __restrict__ vfrag){
  __shared__ bf16_t As[2][64*64];   // 16 KB (reused as epilogue stage)
  __shared__ bf16_t Bs[2][128*64];  // 32 KB
  int l = ((int)blockIdx.x & 7)*144 + ((int)blockIdx.x >> 3);
  int x = l & 63, y = l >> 6;       // x: 64 row tiles (64 rows), y: 18 col tiles (128 cols)
  f32x4 acc[2][4] = {};
  const bf16_t* A; const bf16_t* W; int c0;
  if (y < 6){ A = qn;  W = wq;  c0 = y*128; }
  else      { A = kvb; W = wkv; c0 = (y-6)*128; }
  gemm_core_db<64,128>(A, W, D_, x*64, c0, As[0], As[1], Bs[0], Bs[1], acc);
  // loop ends with __syncthreads -> LDS free for reuse

  bf16_t* stage = &As[0][0];        // 8192 bf16 = 16 KB = 4 chunks x 2048
  const int lane = threadIdx.x & 63;
  const int wv   = threadIdx.x >> 6;
  const int wr = wv >> 1, wc = wv & 1;
  const int l4 = lane >> 4, lm = lane & 15;
  const int row0 = x*64;
  const int bb = row0 >> 10;
  const int t0 = (row0 & 1023) >> 5;
  const int chunk = (wc*2 + wr)*2048;

  if (y < 12){
    const float scale = (y < 6) ? 0.125f*LOG2E : 1.0f;
    const int* pos = (y < 6) ? posq : posk;
    const float* bias = (y < 6) ? bq : bkv;
    bf16_t* gdst = (y < 6) ? qh : kh;
    const int h0 = c0 >> 6;
    const int par = lm & 1;
#pragma unroll
    for (int ni=0;ni<4;ni++){
      int col = c0 + wc*64 + ni*16 + lm;
      int f = (col & 63) >> 1;
      float F1 = freqs[(col>>6)*32 + f];
      float F2 = freqs[H_*32 + (col>>6)*32 + f];
      float bv = bias[col];
      int cc = f >> 3, hh = (f >> 2) & 1;
      int ebase = chunk + cc*512 + hh*256 + (f&3)*2 + par;
#pragma unroll
      for (int mi=0;mi<2;mi++){
#pragma unroll
        for (int j=0;j<4;j++){
          int row = row0 + wr*32 + mi*16 + l4*4 + j;
          float v = acc[mi][ni][j] + bv;
          float vp = __shfl_xor(v, 1, 64);
          float p0 = (float)pos[row*2+0], p1 = (float)pos[row*2+1];
          float ang = p0*F1 + p1*F2;
          float sn, cs;
          __sincosf(ang, &sn, &cs);
          float outv = (par ? (vp*sn + v*cs) : (v*cs - vp*sn)) * scale;
          int lq2 = mi*16 + l4*4 + j;
          stage[ebase + lq2*8] = (bf16_t)outv;
        }
      }
    }
    __syncthreads();
#pragma unroll
    for (int ch=0; ch<4; ch++){
      int hsel = ch >> 1, tsel = ch & 1;
      size_t gbase = ((size_t)((bb*H_ + h0 + hsel)*32 + t0 + tsel))*2048;
      *reinterpret_cast<bf16x8*>(gdst + gbase + threadIdx.x*8) =
          *reinterpret_cast<const bf16x8*>(stage + ch*2048 + threadIdx.x*8);
    }
  } else {
    const int h0v = (c0 - D_) >> 6;
#pragma unroll
    for (int ni=0;ni<4;ni++){
      int col = c0 + wc*64 + ni*16 + lm;
      int d = ni*16 + lm;               // within-head col
      float bv = bkv[col];
      int dbase = chunk + (d>>5)*1024 + (d&31)*8;
#pragma unroll
      for (int mi=0;mi<2;mi++){
#pragma unroll
        for (int j=0;j<4;j++){
          float v = acc[mi][ni][j] + bv;
          int lq2 = mi*16 + l4*4 + j;
          int ks = (lq2>>4)&1, hi2 = (lq2>>3)&1, jj = lq2&7;
          stage[dbase + ks*512 + hi2*256 + jj] = (bf16_t)v;
        }
      }
    }
    __syncthreads();
#pragma unroll
    for (int ch=0; ch<4; ch++){
      int hsel = ch >> 1, kbsel = ch & 1;
      size_t gbase = ((size_t)((bb*H_ + h0v + hsel)*32 + t0 + kbsel))*2048;
      *reinterpret_cast<bf16x8*>(vfrag + gbase + threadIdx.x*8) =
          *reinterpret_cast<const bf16x8*>(stage + ch*2048 + threadIdx.x*8);
    }
  }
}

// ---------------- one attention step: QK^T -> exp2 -> P repack -> PV ----------------
__device__ __forceinline__ void attn_step(const bf16x8 (&kf)[4], const bf16x8 (&vf)[4],
                                          const bf16x8 (&qf)[4], f32x16 (&acc_o)[2],
                                          float &psum){
  f32x16 accs = {};
#pragma unroll
  for (int c=0;c<4;c++)
    accs = __builtin_amdgcn_mfma_f32_32x32x16_bf16(kf[c], qf[c], accs, 0,0,0);
#pragma unroll
  for (int r=0;r<16;r++){
    float v = exp2f(accs[r]);
    accs[r] = v;
    psum += v;
  }
  bf16x8 pa[2];
#pragma unroll
  for (int ks=0;ks<2;ks++){
    const int base = ks*8;
    unsigned int a0 = cvtpk(accs[base+0], accs[base+1]);
    unsigned int a1 = cvtpk(accs[base+2], accs[base+3]);
    unsigned int b0 = cvtpk(accs[base+4], accs[base+5]);
    unsigned int b1 = cvtpk(accs[base+6], accs[base+7]);
    plswap(a0, b0);
    plswap(a1, b1);
    u32x4 w; w[0]=a0; w[1]=a1; w[2]=b0; w[3]=b1;
    pa[ks] = __builtin_bit_cast(bf16x8, w);
  }
#pragma unroll
  for (int dt=0;dt<2;dt++)
#pragma unroll
    for (int ks=0;ks<2;ks++)
      acc_o[dt] = __builtin_amdgcn_mfma_f32_32x32x16_bf16(pa[ks], vf[dt*2+ks], acc_o[dt], 0,0,0);
}

// ---------------- flash attention (R13 kernel, unchanged) ----------------
__global__ __launch_bounds__(256, 3)
void attn_kernel(const bf16_t* __restrict__ Qf, const bf16_t* __restrict__ Kf,
                 const bf16_t* __restrict__ Vf, bf16_t* __restrict__ Oh){
  const int lane = threadIdx.x & 63;
  const int wv   = threadIdx.x >> 6;  // key-quarter 0..3
  const int hi = lane >> 5, lq = lane & 31;
  int l = ((int)blockIdx.x & 7)*192 + ((int)blockIdx.x >> 3);
  const int bh = l >> 5;
  const int qt = l & 31;
  const int q0 = qt*32;
  const int b = bh / H_, h = bh % H_;
  const size_t headoff = ((size_t)b*S_*H_ + h)*HD_;

  __shared__ float part[4][64][33];
  __shared__ float ps[4][32];

  bf16x8 qf[4];
  {
    const bf16_t* qp_ = Qf + (size_t)(bh*32 + qt)*2048 + lane*8;
#pragma unroll
    for (int c=0;c<4;c++)
      qf[c] = *reinterpret_cast<const bf16x8*>(qp_ + c*512);
  }

  const bf16_t* kbase = Kf + ((size_t)bh*32 + wv*8)*2048 + lane*8;
  const bf16_t* vbase = Vf + ((size_t)bh*32 + wv*8)*2048 + lane*8;

  float psum = 0.f;
  f32x16 acc_o[2] = {};

  bf16x8 kfA[4], kfB[4], vf[4];
#pragma unroll
  for (int c=0;c<4;c++)
    kfA[c] = *reinterpret_cast<const bf16x8*>(kbase + c*512);

#pragma unroll
  for (int t=0; t<4; ++t){
    {
      const bf16_t* vp = vbase + (size_t)(2*t)*2048;
#pragma unroll
      for (int j=0;j<4;j++) vf[j] = *reinterpret_cast<const bf16x8*>(vp + j*512);
      const bf16_t* kp = kbase + (size_t)(2*t+1)*2048;
#pragma unroll
      for (int c=0;c<4;c++) kfB[c] = *reinterpret_cast<const bf16x8*>(kp + c*512);
      attn_step(kfA, vf, qf, acc_o, psum);
    }
    {
      const bf16_t* vp = vbase + (size_t)(2*t+1)*2048;
#pragma unroll
      for (int j=0;j<4;j++) vf[j] = *reinterpret_cast<const bf16x8*>(vp + j*512);
      if (t < 3){
        const bf16_t* kp = kbase + (size_t)(2*t+2)*2048;
#pragma unroll
        for (int c=0;c<4;c++) kfA[c] = *reinterpret_cast<const bf16x8*>(kp + c*512);
      }
      attn_step(kfB, vf, qf, acc_o, psum);
    }
  }

  float tp = psum + __shfl_xor(psum, 32, 64);
#pragma unroll
  for (int dt=0;dt<2;dt++)
#pragma unroll
    for (int r=0;r<16;r++)
      part[wv][lane][dt*16+r] = acc_o[dt][r];
  if (lane < 32) ps[wv][lq] = tp;
  __syncthreads();

  const int dt = wv >> 1;
  const int rbase = (wv & 1)*8;
  float tot = ps[0][lq] + ps[1][lq] + ps[2][lq] + ps[3][lq];
  float inv = 1.0f / tot;

  bf16_t* obase = Oh + headoff;
#pragma unroll
  for (int ri=0;ri<8;ri++){
    int r = rbase + ri;
    float s = part[0][lane][dt*16+r] + part[1][lane][dt*16+r]
            + part[2][lane][dt*16+r] + part[3][lane][dt*16+r];
    float invr = __shfl(inv, (r&3) + 8*(r>>2) + 4*hi, 64);
    int qq = q0 + (r&3) + 8*(r>>2) + 4*hi;
    obase[(size_t)qq*RSTRIDE + dt*32 + lq] = (bf16_t)(s*invr);
  }
}

// ---------------- launch ----------------
extern "C" void kernel_launch(void* const* d_in, const int* in_sizes, int n_in,
                              void* d_out, int out_size, void* d_ws, size_t ws_size,
                              hipStream_t stream) {
  const float* q      = (const float*)d_in[0];
  const float* kv     = (const float*)d_in[1];
  const int*   posq   = (const int*)d_in[2];
  const int*   posk   = (const int*)d_in[3];
  const float* w_norm = (const float*)d_in[4];
  const float* w_q    = (const float*)d_in[5];
  const float* b_q    = (const float*)d_in[6];
  const float* w_kv   = (const float*)d_in[7];
  const float* b_kv   = (const float*)d_in[8];
  const float* w_out  = (const float*)d_in[9];
  const float* b_out  = (const float*)d_in[10];
  const float* freqs  = (const float*)d_in[11];
  float* out = (float*)d_out;

  char* p = (char*)d_ws;
  bf16_t* qn   = (bf16_t*)p; p += (size_t)NROW*D_*2;
  bf16_t* kvb  = (bf16_t*)p; p += (size_t)NROW*D_*2;
  bf16_t* wqb  = (bf16_t*)p; p += (size_t)D_*D_*2;
  bf16_t* wkvb = (bf16_t*)p; p += (size_t)2*D_*D_*2;
  bf16_t* wob  = (bf16_t*)p; p += (size_t)D_*D_*2;
  bf16_t* qh   = (bf16_t*)p; p += (size_t)NROW*D_*2;    // Q fragments
  bf16_t* kh   = (bf16_t*)p; p += (size_t)NROW*D_*2;    // K fragments
  bf16_t* vt   = (bf16_t*)p; p += (size_t)NBH*HD_*S_*2; // V fragments
  bf16_t* oh   = (bf16_t*)p; p += (size_t)NROW*D_*2;

  // 1) RMSNorm + all casts
  prep_kernel<<<NROW + 5376, 256, 0, stream>>>(q, w_norm, qn,
                                               w_q, wqb, w_kv, wkvb, w_out, wob, kv, kvb);
  // 2) q-proj + kv-proj GEMM (64x128 dbuf) + LDS-staged RoPE/pack epilogues
  gemm_qkv_kernel<<<1152, 256, 0, stream>>>(qn, kvb, wqb, wkvb, b_q, b_kv,
                                            posq, posk, freqs, qh, kh, vt);
  // 3) attention (R13 kernel)
  attn_kernel<<<1536, 256, 0, stream>>>(qh, kh, vt, oh);
  // 4) output projection (64x64 dbuf) -> f32 d_out
  gemm_kernel<<<768, 256, 0, stream>>>(oh, wob, b_out, out, D_, D_);
}

// Round 24
// 75.067 us; speedup vs baseline: 1.1971x; 1.0274x over previous
//
#include <hip/hip_runtime.h>

#define B_   4
#define S_   1024
#define D_   768
#define H_   12
#define HD_  64
#define NROW (B_*S_)          // 4096
#define RSTRIDE (H_*HD_)      // 768
#define NBH  (B_*H_)          // 48
#define LOG2E 1.44269504f

typedef __bf16 bf16_t;
typedef bf16_t bf16x8 __attribute__((ext_vector_type(8)));
typedef float  f32x4  __attribute__((ext_vector_type(4)));
typedef float  f32x16 __attribute__((ext_vector_type(16)));
typedef unsigned int u32x4 __attribute__((ext_vector_type(4)));

__device__ __forceinline__ unsigned short bf16b(float f){
  bf16_t b = (bf16_t)f;
  return __builtin_bit_cast(unsigned short, b);
}

__device__ __forceinline__ void gload16(const void* g, void* l){
  __builtin_amdgcn_global_load_lds(
      (const __attribute__((address_space(1))) void*)g,
      (__attribute__((address_space(3))) void*)l, 16, 0, 0);
}

__device__ __forceinline__ unsigned int cvtpk(float lo, float hi){
  unsigned int r;
  asm("v_cvt_pk_bf16_f32 %0, %1, %2" : "=v"(r) : "v"(lo), "v"(hi));
  return r;
}

__device__ __forceinline__ void plswap(unsigned int &a, unsigned int &b){
  asm volatile("v_permlane32_swap_b32 %0, %1" : "+v"(a), "+v"(b));
}

// ---------------- fused prep: RMSNorm(q) + all f32->bf16 casts, one launch ----------------
__global__ void prep_kernel(const float* __restrict__ q, const float* __restrict__ w_norm,
                            bf16_t* __restrict__ qn,
                            const float* __restrict__ wq,  bf16_t* __restrict__ wqb,
                            const float* __restrict__ wkv, bf16_t* __restrict__ wkvb,
                            const float* __restrict__ wo,  bf16_t* __restrict__ wob,
                            const float* __restrict__ kv,  bf16_t* __restrict__ kvb){
  int bid = blockIdx.x;
  if (bid < NROW){
    int row = bid;
    const float* src = q + (size_t)row*D_;
    float vals[3]; float ss = 0.f;
#pragma unroll
    for (int i=0;i<3;i++){ float v = src[threadIdx.x + i*256]; vals[i]=v; ss += v*v; }
#pragma unroll
    for (int m=1;m<64;m<<=1) ss += __shfl_xor(ss, m, 64);
    __shared__ float red[4];
    if ((threadIdx.x & 63) == 0) red[threadIdx.x>>6] = ss;
    __syncthreads();
    float tot = red[0]+red[1]+red[2]+red[3];
    float rs = rsqrtf(tot*(1.0f/D_) + 1e-5f);
#pragma unroll
    for (int i=0;i<3;i++){
      int c = threadIdx.x + i*256;
      qn[(size_t)row*D_ + c] = (bf16_t)(vals[i]*rs*w_norm[c]);
    }
  } else {
    int i = (bid - NROW)*256 + threadIdx.x;
    const int n0 = D_*D_/4, n1 = 2*D_*D_/4, n2 = D_*D_/4, n3 = NROW*D_/4;
    const float* s; bf16_t* d; int off;
    if (i < n0){ s = wq; d = wqb; off = i; }
    else if (i < n0+n1){ s = wkv; d = wkvb; off = i - n0; }
    else if (i < n0+n1+n2){ s = wo; d = wob; off = i - n0 - n1; }
    else if (i < n0+n1+n2+n3){ s = kv; d = kvb; off = i - n0 - n1 - n2; }
    else return;
    float4 v = reinterpret_cast<const float4*>(s)[off];
    ushort4 o;
    o.x = bf16b(v.x); o.y = bf16b(v.y); o.z = bf16b(v.z); o.w = bf16b(v.w);
    reinterpret_cast<ushort4*>(d)[off] = o;
  }
}

// ---------------- GEMM building blocks: BK=64 swizzled, 256 thr, 2x2 waves ----------------
template<int TM, int TN>
__device__ __forceinline__ void stage_t(const bf16_t* __restrict__ A, const bf16_t* __restrict__ W,
                                        int K, int row0, int col0, int kt,
                                        bf16_t* As, bf16_t* Bs){
  const int tid = threadIdx.x;
  const int wv  = tid >> 6;
#pragma unroll
  for (int i=0;i<TM/32;i++){
    int c = i*256 + tid;
    int r = c >> 3, kc = (c & 7) ^ (r & 7);
    gload16(A + (size_t)(row0+r)*K + kt + kc*8, As + (size_t)(i*256 + wv*64)*8);
  }
#pragma unroll
  for (int i=0;i<TN/32;i++){
    int c = i*256 + tid;
    int r = c >> 3, kc = (c & 7) ^ (r & 7);
    gload16(W + (size_t)(col0+r)*K + kt + kc*8, Bs + (size_t)(i*256 + wv*64)*8);
  }
}

template<int TM, int TN>
__device__ __forceinline__ void compute_t(const bf16_t* As, const bf16_t* Bs,
                                          f32x4 (&acc)[TM/32][TN/32]){
  const int lane = threadIdx.x & 63;
  const int wv   = threadIdx.x >> 6;
  const int wr = wv >> 1, wc = wv & 1;
  const int l4 = lane >> 4, lm = lane & 15;
#pragma unroll
  for (int kk=0; kk<2; kk++){
    bf16x8 af[TM/32], bfr[TN/32];
#pragma unroll
    for (int mi=0;mi<TM/32;mi++){
      int r = wr*(TM/2) + mi*16 + lm;
      int s = (kk*4 + l4) ^ (r & 7);
      af[mi] = *reinterpret_cast<const bf16x8*>(As + r*64 + s*8);
    }
#pragma unroll
    for (int ni=0;ni<TN/32;ni++){
      int r = wc*(TN/2) + ni*16 + lm;
      int s = (kk*4 + l4) ^ (r & 7);
      bfr[ni] = *reinterpret_cast<const bf16x8*>(Bs + r*64 + s*8);
    }
#pragma unroll
    for (int mi=0;mi<TM/32;mi++)
#pragma unroll
      for (int ni=0;ni<TN/32;ni++)
        acc[mi][ni] = __builtin_amdgcn_mfma_f32_16x16x32_bf16(af[mi], bfr[ni], acc[mi][ni], 0,0,0);
  }
}

// Double-buffered core (T3-minimum 2-phase): issue STAGE(t+1) BEFORE compute(t);
// single __syncthreads() per tile. Best-measured GEMM structure (R19).
template<int TM, int TN>
__device__ __forceinline__ void gemm_core_db(const bf16_t* __restrict__ A, const bf16_t* __restrict__ W,
                                             int K, int row0, int col0,
                                             bf16_t* As0, bf16_t* As1, bf16_t* Bs0, bf16_t* Bs1,
                                             f32x4 (&acc)[TM/32][TN/32]){
  stage_t<TM,TN>(A, W, K, row0, col0, 0, As0, Bs0);
  __syncthreads();
  const int nt = K/64;
  bf16_t *Ac = As0, *An = As1, *Bc = Bs0, *Bn = Bs1;
  for (int t=0; t<nt; ++t){
    if (t+1 < nt)
      stage_t<TM,TN>(A, W, K, row0, col0, (t+1)*64, An, Bn);
    compute_t<TM,TN>(Ac, Bc, acc);
    __syncthreads();
    bf16_t* tmp;
    tmp = Ac; Ac = An; An = tmp;
    tmp = Bc; Bc = Bn; Bn = tmp;
  }
}

// ---------------- out-proj: 64x64 tiles, dbuf (768 blocks), bias + f32 write ----------------
__global__ void gemm_kernel(const bf16_t* __restrict__ A, const bf16_t* __restrict__ W,
                            const float* __restrict__ bias, float* __restrict__ C,
                            int N, int K){
  __shared__ bf16_t As[2][64*64];
  __shared__ bf16_t Bs[2][64*64];
  int l = ((int)blockIdx.x & 7)*96 + ((int)blockIdx.x >> 3);
  int x = l & 63, y = l >> 6;       // 64 row tiles x 12 col tiles
  f32x4 acc[2][2] = {};
  gemm_core_db<64,64>(A, W, K, x*64, y*64, As[0], As[1], Bs[0], Bs[1], acc);
  const int lane = threadIdx.x & 63;
  const int wv   = threadIdx.x >> 6;
  const int wr = wv >> 1, wc = wv & 1;
  const int l4 = lane >> 4, lm = lane & 15;
  const int row0 = x*64, col0 = y*64;
#pragma unroll
  for (int mi=0;mi<2;mi++){
#pragma unroll
    for (int ni=0;ni<2;ni++){
      int col = col0 + wc*32 + ni*16 + lm;
      float bv = bias[col];
#pragma unroll
      for (int j=0;j<4;j++){
        int row = row0 + wr*32 + mi*16 + l4*4 + j;
        C[(size_t)row*N + col] = acc[mi][ni][j] + bv;
      }
    }
  }
}

// ---------------- fused epilogue: bias + RoPE + fragment-pack (q or k), TM=64/TN=128 ----------------
__device__ __forceinline__ void epi_rope(f32x4 (&acc)[2][4], const float* __restrict__ bias,
                                         const int* __restrict__ pos, const float* __restrict__ freqs,
                                         bf16_t* __restrict__ dst, int row0, int col0, float scale){
  const int lane = threadIdx.x & 63;
  const int wv   = threadIdx.x >> 6;
  const int wr = wv >> 1, wc = wv & 1;
  const int l4 = lane >> 4, lm = lane & 15;
  const int par = lm & 1;
#pragma unroll
  for (int ni=0;ni<4;ni++){
    int col = col0 + wc*64 + ni*16 + lm;
    int h = col >> 6, hd = col & 63, f = hd >> 1;
    float F1 = freqs[h*32 + f];
    float F2 = freqs[H_*32 + h*32 + f];
    float bv = bias[col];
    int cc = f >> 3, hi = (f >> 2) & 1;
    int ebase = cc*512 + hi*256 + (f&3)*2 + par;
#pragma unroll
    for (int mi=0;mi<2;mi++){
#pragma unroll
      for (int j=0;j<4;j++){
        int row = row0 + wr*32 + mi*16 + l4*4 + j;
        float v = acc[mi][ni][j] + bv;
        float vp = __shfl_xor(v, 1, 64);
        float p0 = (float)pos[row*2+0], p1 = (float)pos[row*2+1];
        float ang = p0*F1 + p1*F2;
        float sn, cs;
        __sincosf(ang, &sn, &cs);
        float out = (par ? (vp*sn + v*cs) : (v*cs - vp*sn)) * scale;
        int b = row >> 10, s = row & 1023;
        int bh = b*H_ + h, tile = s >> 5, lq = s & 31;
        dst[((size_t)(bh*32 + tile))*2048 + ebase + lq*8] = (bf16_t)out;
      }
    }
  }
}

// ---------------- fused epilogue: bias + V fragment-pack (transpose), TM=64/TN=128 ----------------
__device__ __forceinline__ void epi_vpack(f32x4 (&acc)[2][4], const float* __restrict__ bias,
                                          bf16_t* __restrict__ vfrag, int row0, int col0){
  const int lane = threadIdx.x & 63;
  const int wv   = threadIdx.x >> 6;
  const int wr = wv >> 1, wc = wv & 1;
  const int l4 = lane >> 4, lm = lane & 15;
#pragma unroll
  for (int ni=0;ni<4;ni++){
    int col = col0 + wc*64 + ni*16 + lm;
    int vcol = col - D_;
    int h = vcol >> 6, d = vcol & 63;
    int dt = d >> 5, lq2 = d & 31;
    float bv = bias[col];
    int ebase = dt*1024 + lq2*8;
#pragma unroll
    for (int mi=0;mi<2;mi++){
#pragma unroll
      for (int j=0;j<4;j++){
        int row = row0 + wr*32 + mi*16 + l4*4 + j;
        int b = row >> 10, s = row & 1023;
        int bh = b*H_ + h;
        int kb = s >> 5, ks = (s >> 4) & 1, hi2 = (s >> 3) & 1, jj = s & 7;
        vfrag[((size_t)(bh*32 + kb))*2048 + ebase + ks*512 + hi2*256 + jj]
            = (bf16_t)(acc[mi][ni][j] + bv);
      }
    }
  }
}

// ---------------- fused q-proj + kv-proj + RoPE + pack: 64x128 tiles, dbuf, 1152 blocks ----------------
__global__ void gemm_qkv_kernel(const bf16_t* __restrict__ qn, const bf16_t* __restrict__ kvb,
                                const bf16_t* __restrict__ wq, const bf16_t* __restrict__ wkv,
                                const float* __restrict__ bq, const float* __restrict__ bkv,
                                const int* __restrict__ posq, const int* __restrict__ posk,
                                const float* __restrict__ freqs,
                                bf16_t* __restrict__ qh, bf16_t* __restrict__ kh,
                                bf16_t* __restrict__ vfrag){
  __shared__ bf16_t As[2][64*64];
  __shared__ bf16_t Bs[2][128*64];
  int l = ((int)blockIdx.x & 7)*144 + ((int)blockIdx.x >> 3);
  int x = l & 63, y = l >> 6;       // x: 64 row tiles (64 rows), y: 18 col tiles (128 cols)
  f32x4 acc[2][4] = {};
  if (y < 6){
    gemm_core_db<64,128>(qn, wq, D_, x*64, y*128, As[0], As[1], Bs[0], Bs[1], acc);
    epi_rope(acc, bq, posq, freqs, qh, x*64, y*128, 0.125f*LOG2E);
  } else {
    int c0 = (y-6)*128;
    gemm_core_db<64,128>(kvb, wkv, D_, x*64, c0, As[0], As[1], Bs[0], Bs[1], acc);
    if (y < 12)
      epi_rope(acc, bkv, posk, freqs, kh, x*64, c0, 1.0f);   // K half
    else
      epi_vpack(acc, bkv, vfrag, x*64, c0);                  // V half
  }
}

// ---------------- one attention step: QK^T -> exp2 -> P repack -> PV ----------------
__device__ __forceinline__ void attn_step(const bf16x8 (&kf)[4], const bf16x8 (&vf)[4],
                                          const bf16x8 (&qf)[4], f32x16 (&acc_o)[2],
                                          float &psum){
  f32x16 accs = {};
#pragma unroll
  for (int c=0;c<4;c++)
    accs = __builtin_amdgcn_mfma_f32_32x32x16_bf16(kf[c], qf[c], accs, 0,0,0);
#pragma unroll
  for (int r=0;r<16;r++){
    float v = exp2f(accs[r]);
    accs[r] = v;
    psum += v;
  }
  bf16x8 pa[2];
#pragma unroll
  for (int ks=0;ks<2;ks++){
    const int base = ks*8;
    unsigned int a0 = cvtpk(accs[base+0], accs[base+1]);
    unsigned int a1 = cvtpk(accs[base+2], accs[base+3]);
    unsigned int b0 = cvtpk(accs[base+4], accs[base+5]);
    unsigned int b1 = cvtpk(accs[base+6], accs[base+7]);
    plswap(a0, b0);
    plswap(a1, b1);
    u32x4 w; w[0]=a0; w[1]=a1; w[2]=b0; w[3]=b1;
    pa[ks] = __builtin_bit_cast(bf16x8, w);
  }
#pragma unroll
  for (int dt=0;dt<2;dt++)
#pragma unroll
    for (int ks=0;ks<2;ks++)
      acc_o[dt] = __builtin_amdgcn_mfma_f32_32x32x16_bf16(pa[ks], vf[dt*2+ks], acc_o[dt], 0,0,0);
}

// ---------------- flash attention (R13 kernel, best measured; unchanged) ----------------
__global__ __launch_bounds__(256, 3)
void attn_kernel(const bf16_t* __restrict__ Qf, const bf16_t* __restrict__ Kf,
                 const bf16_t* __restrict__ Vf, bf16_t* __restrict__ Oh){
  const int lane = threadIdx.x & 63;
  const int wv   = threadIdx.x >> 6;  // key-quarter 0..3
  const int hi = lane >> 5, lq = lane & 31;
  int l = ((int)blockIdx.x & 7)*192 + ((int)blockIdx.x >> 3);
  const int bh = l >> 5;
  const int qt = l & 31;
  const int q0 = qt*32;
  const int b = bh / H_, h = bh % H_;
  const size_t headoff = ((size_t)b*S_*H_ + h)*HD_;

  __shared__ float part[4][64][33];
  __shared__ float ps[4][32];

  bf16x8 qf[4];
  {
    const bf16_t* qp_ = Qf + (size_t)(bh*32 + qt)*2048 + lane*8;
#pragma unroll
    for (int c=0;c<4;c++)
      qf[c] = *reinterpret_cast<const bf16x8*>(qp_ + c*512);
  }

  const bf16_t* kbase = Kf + ((size_t)bh*32 + wv*8)*2048 + lane*8;
  const bf16_t* vbase = Vf + ((size_t)bh*32 + wv*8)*2048 + lane*8;

  float psum = 0.f;
  f32x16 acc_o[2] = {};

  bf16x8 kfA[4], kfB[4], vf[4];
#pragma unroll
  for (int c=0;c<4;c++)
    kfA[c] = *reinterpret_cast<const bf16x8*>(kbase + c*512);

#pragma unroll
  for (int t=0; t<4; ++t){
    {
      const bf16_t* vp = vbase + (size_t)(2*t)*2048;
#pragma unroll
      for (int j=0;j<4;j++) vf[j] = *reinterpret_cast<const bf16x8*>(vp + j*512);
      const bf16_t* kp = kbase + (size_t)(2*t+1)*2048;
#pragma unroll
      for (int c=0;c<4;c++) kfB[c] = *reinterpret_cast<const bf16x8*>(kp + c*512);
      attn_step(kfA, vf, qf, acc_o, psum);
    }
    {
      const bf16_t* vp = vbase + (size_t)(2*t+1)*2048;
#pragma unroll
      for (int j=0;j<4;j++) vf[j] = *reinterpret_cast<const bf16x8*>(vp + j*512);
      if (t < 3){
        const bf16_t* kp = kbase + (size_t)(2*t+2)*2048;
#pragma unroll
        for (int c=0;c<4;c++) kfA[c] = *reinterpret_cast<const bf16x8*>(kp + c*512);
      }
      attn_step(kfB, vf, qf, acc_o, psum);
    }
  }

  float tp = psum + __shfl_xor(psum, 32, 64);
#pragma unroll
  for (int dt=0;dt<2;dt++)
#pragma unroll
    for (int r=0;r<16;r++)
      part[wv][lane][dt*16+r] = acc_o[dt][r];
  if (lane < 32) ps[wv][lq] = tp;
  __syncthreads();

  const int dt = wv >> 1;
  const int rbase = (wv & 1)*8;
  float tot = ps[0][lq] + ps[1][lq] + ps[2][lq] + ps[3][lq];
  float inv = 1.0f / tot;

  bf16_t* obase = Oh + headoff;
#pragma unroll
  for (int ri=0;ri<8;ri++){
    int r = rbase + ri;
    float s = part[0][lane][dt*16+r] + part[1][lane][dt*16+r]
            + part[2][lane][dt*16+r] + part[3][lane][dt*16+r];
    float invr = __shfl(inv, (r&3) + 8*(r>>2) + 4*hi, 64);
    int qq = q0 + (r&3) + 8*(r>>2) + 4*hi;
    obase[(size_t)qq*RSTRIDE + dt*32 + lq] = (bf16_t)(s*invr);
  }
}

// ---------------- launch ----------------
extern "C" void kernel_launch(void* const* d_in, const int* in_sizes, int n_in,
                              void* d_out, int out_size, void* d_ws, size_t ws_size,
                              hipStream_t stream) {
  const float* q      = (const float*)d_in[0];
  const float* kv     = (const float*)d_in[1];
  const int*   posq   = (const int*)d_in[2];
  const int*   posk   = (const int*)d_in[3];
  const float* w_norm = (const float*)d_in[4];
  const float* w_q    = (const float*)d_in[5];
  const float* b_q    = (const float*)d_in[6];
  const float* w_kv   = (const float*)d_in[7];
  const float* b_kv   = (const float*)d_in[8];
  const float* w_out  = (const float*)d_in[9];
  const float* b_out  = (const float*)d_in[10];
  const float* freqs  = (const float*)d_in[11];
  float* out = (float*)d_out;

  char* p = (char*)d_ws;
  bf16_t* qn   = (bf16_t*)p; p += (size_t)NROW*D_*2;
  bf16_t* kvb  = (bf16_t*)p; p += (size_t)NROW*D_*2;
  bf16_t* wqb  = (bf16_t*)p; p += (size_t)D_*D_*2;
  bf16_t* wkvb = (bf16_t*)p; p += (size_t)2*D_*D_*2;
  bf16_t* wob  = (bf16_t*)p; p += (size_t)D_*D_*2;
  bf16_t* qh   = (bf16_t*)p; p += (size_t)NROW*D_*2;    // Q fragments
  bf16_t* kh   = (bf16_t*)p; p += (size_t)NROW*D_*2;    // K fragments
  bf16_t* vt   = (bf16_t*)p; p += (size_t)NBH*HD_*S_*2; // V fragments
  bf16_t* oh   = (bf16_t*)p; p += (size_t)NROW*D_*2;

  // 1) RMSNorm + all casts
  prep_kernel<<<NROW + 5376, 256, 0, stream>>>(q, w_norm, qn,
                                               w_q, wqb, w_kv, wkvb, w_out, wob, kv, kvb);
  // 2) q-proj + kv-proj GEMM (64x128, double-buffered, prefetch-before-compute)
  gemm_qkv_kernel<<<1152, 256, 0, stream>>>(qn, kvb, wqb, wkvb, b_q, b_kv,
                                            posq, posk, freqs, qh, kh, vt);
  // 3) attention (R13 kernel)
  attn_kernel<<<1536, 256, 0, stream>>>(qh, kh, vt, oh);
  // 4) output projection (64x64, double-buffered) -> f32 d_out
  gemm_kernel<<<768, 256, 0, stream>>>(oh, wob, b_out, out, D_, D_);
}